// Round 1
// baseline (10070.457 us; speedup 1.0000x reference)
//
#include <hip/hip_runtime.h>
#include <hip/hip_bf16.h>
#include <stdint.h>

typedef __attribute__((ext_vector_type(8))) short bf16x8;
typedef __attribute__((ext_vector_type(4))) float f32x4;
typedef __hip_bfloat16 bf16;

static constexpr int B_   = 128;
static constexpr int T_   = 256;
static constexpr int DIN  = 1024;
static constexpr int DDET = 1024;
static constexpr int DSTO = 256;
static constexpr int KGATE = DSTO + DDET;   // 1280
static constexpr int BT   = B_ * T_;        // 32768

__device__ __forceinline__ float bf2f(bf16 v){ return __bfloat162float(v); }
__device__ __forceinline__ bf16  f2bf(float f){ return __float2bfloat16(f); }

__device__ __forceinline__ f32x4 mfma16(bf16x8 a, bf16x8 b, f32x4 c){
  return __builtin_amdgcn_mfma_f32_16x16x32_bf16(a, b, c, 0, 0, 0);
}

__device__ __forceinline__ void gload_lds16(const void* g, void* l){
  __builtin_amdgcn_global_load_lds(
      (const __attribute__((address_space(1))) uint32_t*)g,
      (__attribute__((address_space(3))) uint32_t*)l, 16, 0, 0);
}

// ---------------- conversions / packing ----------------

__global__ __launch_bounds__(256) void k_cvt_bf16(const float* __restrict__ s,
                                                  bf16* __restrict__ d, int n4){
  int i = blockIdx.x * blockDim.x + threadIdx.x;
  if (i >= n4) return;
  float4 v = reinterpret_cast<const float4*>(s)[i];
  union { bf16 b[4]; uint64_t u; } o;
  o.b[0] = f2bf(v.x); o.b[1] = f2bf(v.y); o.b[2] = f2bf(v.z); o.b[3] = f2bf(v.w);
  *reinterpret_cast<uint64_t*>(&d[(size_t)i * 4]) = o.u;
}

// Wcat[n][k] (n<3072, k<1280): k<256 -> W_ih[n][k], else W_hh[n][k-256]
__global__ __launch_bounds__(256) void k_pack_wcat(const float* __restrict__ Wih,
                                                   const float* __restrict__ Whh,
                                                   bf16* __restrict__ W, int total){
  int i = blockIdx.x * blockDim.x + threadIdx.x;
  if (i >= total) return;
  int n = i / KGATE, k = i % KGATE;
  float v = (k < DSTO) ? Wih[(size_t)n * DSTO + k] : Whh[(size_t)n * DDET + (k - DSTO)];
  W[i] = f2bf(v);
}

// Wx[n][k] = x-part (cols 0..1023), Wh[n][k] = h-part (cols 1024..2047)
// rows n<256 -> W_mpost, n>=256 -> W_lvpost
__global__ __launch_bounds__(256) void k_pack_wpost(const float* __restrict__ Wm,
                                                    const float* __restrict__ Wlv,
                                                    bf16* __restrict__ Wx,
                                                    bf16* __restrict__ Wh, int total){
  int i = blockIdx.x * blockDim.x + threadIdx.x;
  if (i >= total) return;
  int n = i / DDET, k = i % DDET;
  const float* src = (n < DSTO) ? Wm : Wlv;
  int r = (n < DSTO) ? n : n - DSTO;
  Wx[i] = f2bf(src[(size_t)r * 2048 + k]);
  Wh[i] = f2bf(src[(size_t)r * 2048 + DIN + k]);
}

// ---------------- scan kernels ----------------
// gates: per step t. grid 128 blocks x 256 thr.
// block: m-tile = bid&1 (64 rows), j-tile = bid>>1 (16 gate cols of 1024)
__global__ __launch_bounds__(256) void k_gates(
    const bf16* __restrict__ z_in, const bf16* __restrict__ h_in,
    const bf16* __restrict__ Wcat, const float* __restrict__ bih,
    const float* __restrict__ bhh, bf16* __restrict__ h_out,
    bf16* __restrict__ dec_in, int t)
{
  int tid = threadIdx.x, lane = tid & 63, wv = tid >> 6;
  int m0 = (blockIdx.x & 1) * 64 + wv * 16;
  int j0 = (blockIdx.x >> 1) * 16;
  int lrow = lane & 15, lkg = lane >> 4;

  f32x4 accR = {0.f,0.f,0.f,0.f}, accU = accR, accX = accR, accH = accR;

  const bf16* wR = Wcat + (size_t)(j0 + lrow) * KGATE;
  const bf16* wU = Wcat + (size_t)(1024 + j0 + lrow) * KGATE;
  const bf16* wN = Wcat + (size_t)(2048 + j0 + lrow) * KGATE;
  const bf16* za = z_in + (size_t)(m0 + lrow) * DSTO;
  const bf16* ha = h_in + (size_t)(m0 + lrow) * DDET;

#pragma unroll 4
  for (int kk = 0; kk < 8; ++kk){            // z part, k in [0,256)
    int k = kk * 32 + lkg * 8;
    bf16x8 a  = *reinterpret_cast<const bf16x8*>(za + k);
    bf16x8 bR = *reinterpret_cast<const bf16x8*>(wR + k);
    bf16x8 bU = *reinterpret_cast<const bf16x8*>(wU + k);
    bf16x8 bN = *reinterpret_cast<const bf16x8*>(wN + k);
    accR = mfma16(a, bR, accR);
    accU = mfma16(a, bU, accU);
    accX = mfma16(a, bN, accX);
  }
#pragma unroll 4
  for (int kk = 0; kk < 32; ++kk){           // h part, Wcat k in [256,1280)
    int k = kk * 32 + lkg * 8;
    bf16x8 a  = *reinterpret_cast<const bf16x8*>(ha + k);
    bf16x8 bR = *reinterpret_cast<const bf16x8*>(wR + DSTO + k);
    bf16x8 bU = *reinterpret_cast<const bf16x8*>(wU + DSTO + k);
    bf16x8 bN = *reinterpret_cast<const bf16x8*>(wN + DSTO + k);
    accR = mfma16(a, bR, accR);
    accU = mfma16(a, bU, accU);
    accH = mfma16(a, bN, accH);
  }

  int col = j0 + lrow;
  float biR = bih[col] + bhh[col];
  float biU = bih[1024 + col] + bhh[1024 + col];
  float biX = bih[2048 + col];
  float biH = bhh[2048 + col];
#pragma unroll
  for (int i = 0; i < 4; ++i){
    int row = m0 + lkg * 4 + i;
    float r = 1.f / (1.f + expf(-(accR[i] + biR)));
    float u = 1.f / (1.f + expf(-(accU[i] + biU)));
    float n = tanhf(accX[i] + biX + r * (accH[i] + biH));
    float hold = bf2f(h_in[(size_t)row * DDET + col]);
    float hn = (1.f - u) * n + u * hold;
    bf16 hb = f2bf(hn);
    h_out[(size_t)row * DDET + col] = hb;
    dec_in[((size_t)row * T_ + t) * KGATE + col] = hb;
  }
}

// posterior: grid 32 blocks x 256 thr. m-tile = bid&1, j-tile = bid>>1 (16 of 256)
__global__ __launch_bounds__(256) void k_post(
    const bf16* __restrict__ h_new, const bf16* __restrict__ Wph,
    const float* __restrict__ bm, const float* __restrict__ blv,
    const float* __restrict__ px, const float* __restrict__ noise,
    bf16* __restrict__ z_out, bf16* __restrict__ dec_in, int t)
{
  int tid = threadIdx.x, lane = tid & 63, wv = tid >> 6;
  int m0 = (blockIdx.x & 1) * 64 + wv * 16;
  int j0 = (blockIdx.x >> 1) * 16;
  int lrow = lane & 15, lkg = lane >> 4;

  f32x4 accM = {0.f,0.f,0.f,0.f}, accL = accM;
  const bf16* wM = Wph + (size_t)(j0 + lrow) * DDET;
  const bf16* wL = Wph + (size_t)(DSTO + j0 + lrow) * DDET;
  const bf16* ha = h_new + (size_t)(m0 + lrow) * DDET;

#pragma unroll 4
  for (int kk = 0; kk < 32; ++kk){
    int k = kk * 32 + lkg * 8;
    bf16x8 a  = *reinterpret_cast<const bf16x8*>(ha + k);
    bf16x8 bM = *reinterpret_cast<const bf16x8*>(wM + k);
    bf16x8 bL = *reinterpret_cast<const bf16x8*>(wL + k);
    accM = mfma16(a, bM, accM);
    accL = mfma16(a, bL, accL);
  }

  int j = j0 + lrow;
#pragma unroll
  for (int i = 0; i < 4; ++i){
    int row = m0 + lkg * 4 + i;
    size_t prow = ((size_t)row * T_ + t) * 512;
    float mean = accM[i] + bm[j] + px[prow + j];
    float lv   = accL[i] + blv[j] + px[prow + DSTO + j];
    float nt   = noise[((size_t)t * B_ + row) * DSTO + j];
    float z = nt * expf(0.5f * lv) + mean;
    bf16 zb = f2bf(z);
    z_out[(size_t)row * DSTO + j] = zb;
    dec_in[((size_t)row * T_ + t) * KGATE + DIN + j] = zb;
  }
}

// ---------------- big GEMM: C[M,N] = A[M,K] @ W[N,K]^T (+bias, epilogue) ----------------
enum { EPI_F32_NOBIAS = 0, EPI_ELU_BF16 = 1, EPI_BIAS_F32 = 2 };

__global__ __launch_bounds__(256) void k_gemm(
    const bf16* __restrict__ A, const bf16* __restrict__ W,
    const float* __restrict__ bias, void* __restrict__ Cout,
    int M, int N, int K, int epi)
{
  __shared__ __align__(16) short As[128 * 32];
  __shared__ __align__(16) short Bs[128 * 32];
  int tid = threadIdx.x, lane = tid & 63, wv = tid >> 6;
  int ntiles = N >> 7;
  int bm = blockIdx.x / ntiles, bn = blockIdx.x % ntiles;
  size_t m0 = (size_t)bm * 128, n0 = (size_t)bn * 128;
  int qm = (wv >> 1) * 64, qn = (wv & 1) * 64;
  int lrow = lane & 15, lkg = lane >> 4;
  int srow = lane >> 2;          // row within 16-row chunk
  int skb  = (lane & 3) * 16;    // byte offset within 64B row

  f32x4 acc[4][4];
#pragma unroll
  for (int a0 = 0; a0 < 4; ++a0)
#pragma unroll
    for (int b0 = 0; b0 < 4; ++b0) acc[a0][b0] = (f32x4){0.f,0.f,0.f,0.f};

  for (int kk = 0; kk < K; kk += 32){
    __syncthreads();
#pragma unroll
    for (int i = 0; i < 2; ++i){
      int c = wv * 2 + i;
      const char* gA = (const char*)(A + (m0 + c * 16 + srow) * (size_t)K + kk) + skb;
      const char* gB = (const char*)(W + (n0 + c * 16 + srow) * (size_t)K + kk) + skb;
      gload_lds16(gA, (char*)As + c * 1024);
      gload_lds16(gB, (char*)Bs + c * 1024);
    }
    __syncthreads();
    bf16x8 af[4], bg[4];
#pragma unroll
    for (int f = 0; f < 4; ++f){
      af[f] = *reinterpret_cast<const bf16x8*>(&As[(qm + f * 16 + lrow) * 32 + lkg * 8]);
      bg[f] = *reinterpret_cast<const bf16x8*>(&Bs[(qn + f * 16 + lrow) * 32 + lkg * 8]);
    }
#pragma unroll
    for (int mf = 0; mf < 4; ++mf)
#pragma unroll
      for (int nf = 0; nf < 4; ++nf)
        acc[mf][nf] = mfma16(af[mf], bg[nf], acc[mf][nf]);
  }

#pragma unroll
  for (int mf = 0; mf < 4; ++mf)
#pragma unroll
    for (int nf = 0; nf < 4; ++nf)
#pragma unroll
      for (int i = 0; i < 4; ++i){
        size_t row = m0 + qm + mf * 16 + lkg * 4 + i;
        size_t col = n0 + qn + nf * 16 + lrow;
        float v = acc[mf][nf][i];
        if (bias) v += bias[col];
        if (epi == EPI_ELU_BF16){
          v = v > 0.f ? v : (expf(v) - 1.f);
          ((bf16*)Cout)[row * N + col] = f2bf(v);
        } else {
          ((float*)Cout)[row * N + col] = v;
        }
      }
}

// ---------------- host ----------------

extern "C" void kernel_launch(void* const* d_in, const int* in_sizes, int n_in,
                              void* d_out, int out_size, void* d_ws, size_t ws_size,
                              hipStream_t stream)
{
  const float* x     = (const float*)d_in[0];
  const float* noise = (const float*)d_in[1];
  const float* Wih   = (const float*)d_in[2];
  const float* Whh   = (const float*)d_in[3];
  const float* bih   = (const float*)d_in[4];
  const float* bhh   = (const float*)d_in[5];
  const float* Wm    = (const float*)d_in[6];
  const float* bm    = (const float*)d_in[7];
  const float* Wlv   = (const float*)d_in[8];
  const float* blv   = (const float*)d_in[9];
  const float* dW0   = (const float*)d_in[10];
  const float* db0   = (const float*)d_in[11];
  const float* dW1   = (const float*)d_in[12];
  const float* db1   = (const float*)d_in[13];
  const float* dW2   = (const float*)d_in[14];
  const float* db2   = (const float*)d_in[15];
  const float* dW3   = (const float*)d_in[16];
  const float* db3   = (const float*)d_in[17];

  char* p = (char*)d_ws;
  auto alloc = [&](size_t bytes)->char*{
    char* r = p; p += (bytes + 255) & ~(size_t)255; return r;
  };
  bf16* Wcat = (bf16*)alloc((size_t)3072 * 1280 * 2);
  bf16* Wpx  = (bf16*)alloc((size_t)512 * 1024 * 2);
  bf16* Wph  = (bf16*)alloc((size_t)512 * 1024 * 2);
  bf16* Wd0  = (bf16*)alloc((size_t)1024 * 1280 * 2);
  bf16* Wd1  = (bf16*)alloc((size_t)1024 * 1024 * 2);
  bf16* Wd2  = (bf16*)alloc((size_t)1024 * 1024 * 2);
  bf16* Wd3  = (bf16*)alloc((size_t)1024 * 1024 * 2);
  bf16* hb   = (bf16*)alloc((size_t)2 * B_ * DDET * 2);
  bf16* zb   = (bf16*)alloc((size_t)2 * B_ * DSTO * 2);
  bf16* Xbf  = (bf16*)alloc((size_t)BT * DIN * 2);     // reused as dec L0
  float* px  = (float*)alloc((size_t)BT * 512 * 4);    // reused as dec L1 (bf16)
  bf16* dec  = (bf16*)alloc((size_t)BT * KGATE * 2);
  (void)ws_size; (void)in_sizes; (void)n_in; (void)out_size;

  hipMemsetAsync(hb, 0, (size_t)2 * B_ * DDET * 2, stream);
  hipMemsetAsync(zb, 0, (size_t)2 * B_ * DSTO * 2, stream);

  // weight conversions
  auto cvt = [&](const float* s, bf16* d, size_t n){
    int n4 = (int)(n / 4);
    k_cvt_bf16<<<(n4 + 255) / 256, 256, 0, stream>>>(s, d, n4);
  };
  cvt(dW0, Wd0, (size_t)1024 * 1280);
  cvt(dW1, Wd1, (size_t)1024 * 1024);
  cvt(dW2, Wd2, (size_t)1024 * 1024);
  cvt(dW3, Wd3, (size_t)1024 * 1024);
  cvt(x,   Xbf, (size_t)BT * DIN);
  {
    int total = 3072 * 1280;
    k_pack_wcat<<<(total + 255) / 256, 256, 0, stream>>>(Wih, Whh, Wcat, total);
  }
  {
    int total = 512 * 1024;
    k_pack_wpost<<<(total + 255) / 256, 256, 0, stream>>>(Wm, Wlv, Wpx, Wph, total);
  }

  // px = X @ Wpx^T  [BT x 512] f32
  k_gemm<<<(BT / 128) * (512 / 128), 256, 0, stream>>>(
      Xbf, Wpx, nullptr, px, BT, 512, DIN, EPI_F32_NOBIAS);

  // scan
  for (int t = 0; t < T_; ++t){
    int par = t & 1;
    bf16* h_in  = hb + (size_t)par * B_ * DDET;
    bf16* h_out = hb + (size_t)(1 - par) * B_ * DDET;
    bf16* z_in  = zb + (size_t)par * B_ * DSTO;
    bf16* z_out = zb + (size_t)(1 - par) * B_ * DSTO;
    k_gates<<<128, 256, 0, stream>>>(z_in, h_in, Wcat, bih, bhh, h_out, dec, t);
    k_post <<< 32, 256, 0, stream>>>(h_out, Wph, bm, blv, px, noise, z_out, dec, t);
  }

  // decoder
  bf16* L0 = Xbf;
  bf16* L1 = (bf16*)px;
  k_gemm<<<(BT / 128) * (1024 / 128), 256, 0, stream>>>(
      dec, Wd0, db0, L0, BT, 1024, KGATE, EPI_ELU_BF16);
  k_gemm<<<(BT / 128) * (1024 / 128), 256, 0, stream>>>(
      L0, Wd1, db1, L1, BT, 1024, 1024, EPI_ELU_BF16);
  k_gemm<<<(BT / 128) * (1024 / 128), 256, 0, stream>>>(
      L1, Wd2, db2, L0, BT, 1024, 1024, EPI_ELU_BF16);
  k_gemm<<<(BT / 128) * (1024 / 128), 256, 0, stream>>>(
      L0, Wd3, db3, d_out, BT, 1024, 1024, EPI_BIAS_F32);
}